// Round 4
// baseline (317.198 us; speedup 1.0000x reference)
//
#include <hip/hip_runtime.h>

#define NN 50000
#define NE 600000
#define FIN 64
#define FHID 128
#define BN_EPS 1e-5f

typedef __attribute__((ext_vector_type(8))) short short8;
typedef __attribute__((ext_vector_type(4))) float f32x4;

// ---- bf16 helpers (finite inputs; RNE) ----
__device__ __forceinline__ unsigned short f2bf(float f) {
  unsigned u = __float_as_uint(f);
  return (unsigned short)((u + 0x7FFFu + ((u >> 16) & 1u)) >> 16);
}
__device__ __forceinline__ float bfs(unsigned short u) {
  return __uint_as_float(((unsigned)u) << 16);
}
__device__ __forceinline__ float bflo(unsigned v) { return __uint_as_float(v << 16); }
__device__ __forceinline__ float bfhi(unsigned v) { return __uint_as_float(v & 0xFFFF0000u); }

// ---------------- edge counting ----------------
__global__ __launch_bounds__(256) void count_kernel(const int* __restrict__ dst,
                                                    int* __restrict__ cnt) {
  int e = blockIdx.x * 256 + threadIdx.x;
  if (e < NE) atomicAdd(&cnt[dst[e]], 1);
}

// ---------------- exclusive scan over cnt (3 kernels) ----------------
__global__ __launch_bounds__(256) void scan1(const int* __restrict__ cnt,
                                             int* __restrict__ partial) {
  int i = blockIdx.x * 256 + threadIdx.x;
  int v = (i < NN) ? cnt[i] : 0;
  __shared__ int sh[256];
  sh[threadIdx.x] = v;
  __syncthreads();
  for (int off = 128; off > 0; off >>= 1) {
    if (threadIdx.x < off) sh[threadIdx.x] += sh[threadIdx.x + off];
    __syncthreads();
  }
  if (threadIdx.x == 0) partial[blockIdx.x] = sh[0];
}

__global__ __launch_bounds__(256) void scan2(int* __restrict__ partial, int nb) {
  __shared__ int sh[256];
  int t = threadIdx.x;
  sh[t] = (t < nb) ? partial[t] : 0;
  __syncthreads();
  for (int off = 1; off < 256; off <<= 1) {
    int v = (t >= off) ? sh[t - off] : 0;
    __syncthreads();
    sh[t] += v;
    __syncthreads();
  }
  partial[t] = (t == 0) ? 0 : sh[t - 1];  // exclusive
}

__global__ __launch_bounds__(256) void scan3(const int* __restrict__ cnt,
                                             const int* __restrict__ partial,
                                             int* __restrict__ rowptr,
                                             float* __restrict__ dis) {
  int i = blockIdx.x * 256 + threadIdx.x;
  int t = threadIdx.x;
  int v = (i < NN) ? cnt[i] : 0;
  __shared__ int sh[256];
  sh[t] = v;
  __syncthreads();
  for (int off = 1; off < 256; off <<= 1) {
    int u = (t >= off) ? sh[t - off] : 0;
    __syncthreads();
    sh[t] += u;
    __syncthreads();
  }
  if (i < NN) {
    rowptr[i] = partial[blockIdx.x] + (sh[t] - v);
    dis[i] = rsqrtf((float)(v + 1));  // deg = indeg + 1 (self loop)
  }
}

// ---------------- CSR bucket fill ----------------
__global__ __launch_bounds__(256) void fill_kernel(const int* __restrict__ src,
                                                   const int* __restrict__ dst,
                                                   const int* __restrict__ rowptr,
                                                   int* __restrict__ fill,
                                                   int* __restrict__ csr_src) {
  int e = blockIdx.x * 256 + threadIdx.x;
  if (e < NE) {
    int d = dst[e];
    int p = atomicAdd(&fill[d], 1);
    csr_src[rowptr[d] + p] = src[e];
  }
}

// ---------------- xs = dis[node] * x  (fp32 -> bf16 prescale) ----------------
__global__ __launch_bounds__(256) void scale_x(const float* __restrict__ x,
                                               const float* __restrict__ dis,
                                               ushort4* __restrict__ xs) {
  int i = blockIdx.x * 256 + threadIdx.x;  // float4 index; grid exact (800000)
  float4 v = ((const float4*)x)[i];
  float d = dis[i >> 4];  // 16 float4 per 64-wide row
  xs[i] = make_ushort4(f2bf(v.x * d), f2bf(v.y * d), f2bf(v.z * d), f2bf(v.w * d));
}

// ---------------- weight prep: B^T in bf16, fragment row-major ---------------
// Bt1[128][64]  = W1^T ; Bt2[128][256] = [Wl;Wr]^T  (col-major over k)
__global__ __launch_bounds__(256) void prep_B(const float* __restrict__ W1,
                                              const float* __restrict__ Wl,
                                              const float* __restrict__ Wr,
                                              short* __restrict__ Bt1,
                                              short* __restrict__ Bt2) {
  int i = blockIdx.x * 256 + threadIdx.x;  // grid exact: 40960 threads
  if (i < 128 * 64) {
    int n = i >> 6, k = i & 63;
    Bt1[i] = (short)f2bf(W1[k * 128 + n]);
  } else {
    int j = i - 128 * 64;  // 128*256
    int n = j >> 8, k = j & 255;
    float wv = (k < 128) ? Wl[k * 128 + n] : Wr[(k - 128) * 128 + n];
    Bt2[j] = (short)f2bf(wv);
  }
}

// ---------------- GCN aggregation: xa = di*(xs[node] + sum_e xs[src]) -------
// one wave per node; 8/4/1-unrolled independent gathers for MLP
__global__ __launch_bounds__(256) void gcn_agg(const unsigned short* __restrict__ xs,
                                               const int* __restrict__ csr_src,
                                               const int* __restrict__ rowptr,
                                               const int* __restrict__ cnt,
                                               const float* __restrict__ dis,
                                               unsigned short* __restrict__ xa) {
  int node = blockIdx.x * 4 + threadIdx.y;
  int lane = threadIdx.x;
  float di = dis[node];
  float acc = bfs(xs[node * FIN + lane]);  // self loop: di * (di*x_node)
  int e = rowptr[node];
  int end = e + cnt[node];
  for (; e + 8 <= end; e += 8) {
    int s0 = csr_src[e + 0], s1 = csr_src[e + 1], s2 = csr_src[e + 2],
        s3 = csr_src[e + 3], s4 = csr_src[e + 4], s5 = csr_src[e + 5],
        s6 = csr_src[e + 6], s7 = csr_src[e + 7];
    float a0 = bfs(xs[s0 * FIN + lane]), a1 = bfs(xs[s1 * FIN + lane]);
    float a2 = bfs(xs[s2 * FIN + lane]), a3 = bfs(xs[s3 * FIN + lane]);
    float a4 = bfs(xs[s4 * FIN + lane]), a5 = bfs(xs[s5 * FIN + lane]);
    float a6 = bfs(xs[s6 * FIN + lane]), a7 = bfs(xs[s7 * FIN + lane]);
    acc += ((a0 + a1) + (a2 + a3)) + ((a4 + a5) + (a6 + a7));
  }
  for (; e + 4 <= end; e += 4) {
    int s0 = csr_src[e + 0], s1 = csr_src[e + 1], s2 = csr_src[e + 2],
        s3 = csr_src[e + 3];
    float a0 = bfs(xs[s0 * FIN + lane]), a1 = bfs(xs[s1 * FIN + lane]);
    float a2 = bfs(xs[s2 * FIN + lane]), a3 = bfs(xs[s3 * FIN + lane]);
    acc += (a0 + a1) + (a2 + a3);
  }
  for (; e < end; ++e) acc += bfs(xs[csr_src[e] * FIN + lane]);
  xa[node * FIN + lane] = f2bf(di * acc);
}

// ---------------- SAGE mean aggregation on bf16 h (128 feats) ---------------
__global__ __launch_bounds__(256) void sage_agg(const unsigned* __restrict__ hb,
                                                const int* __restrict__ csr_src,
                                                const int* __restrict__ rowptr,
                                                const int* __restrict__ cnt,
                                                unsigned* __restrict__ neighb) {
  int node = blockIdx.x * 4 + threadIdx.y;
  int lane = threadIdx.x;  // 2 feats per lane (1 uint = 2 bf16)
  float ax = 0.f, ay = 0.f;
  int num = cnt[node];
  int e = rowptr[node];
  int end = e + num;
  for (; e + 8 <= end; e += 8) {
    int s0 = csr_src[e + 0], s1 = csr_src[e + 1], s2 = csr_src[e + 2],
        s3 = csr_src[e + 3], s4 = csr_src[e + 4], s5 = csr_src[e + 5],
        s6 = csr_src[e + 6], s7 = csr_src[e + 7];
    unsigned v0 = hb[s0 * 64 + lane], v1 = hb[s1 * 64 + lane];
    unsigned v2 = hb[s2 * 64 + lane], v3 = hb[s3 * 64 + lane];
    unsigned v4 = hb[s4 * 64 + lane], v5 = hb[s5 * 64 + lane];
    unsigned v6 = hb[s6 * 64 + lane], v7 = hb[s7 * 64 + lane];
    ax += ((bflo(v0) + bflo(v1)) + (bflo(v2) + bflo(v3))) +
          ((bflo(v4) + bflo(v5)) + (bflo(v6) + bflo(v7)));
    ay += ((bfhi(v0) + bfhi(v1)) + (bfhi(v2) + bfhi(v3))) +
          ((bfhi(v4) + bfhi(v5)) + (bfhi(v6) + bfhi(v7)));
  }
  for (; e + 4 <= end; e += 4) {
    int s0 = csr_src[e + 0], s1 = csr_src[e + 1], s2 = csr_src[e + 2],
        s3 = csr_src[e + 3];
    unsigned v0 = hb[s0 * 64 + lane], v1 = hb[s1 * 64 + lane];
    unsigned v2 = hb[s2 * 64 + lane], v3 = hb[s3 * 64 + lane];
    ax += (bflo(v0) + bflo(v1)) + (bflo(v2) + bflo(v3));
    ay += (bfhi(v0) + bfhi(v1)) + (bfhi(v2) + bfhi(v3));
  }
  for (; e < end; ++e) {
    unsigned v = hb[csr_src[e] * 64 + lane];
    ax += bflo(v);
    ay += bfhi(v);
  }
  float inv = 1.0f / fmaxf((float)num, 1.0f);
  neighb[node * 64 + lane] =
      (unsigned)f2bf(ax * inv) | ((unsigned)f2bf(ay * inv) << 16);
}

// ---------------- MFMA bf16 GEMM, all operands from global/L2 ---------------
// C[NN,128] = A1[NN,K1]@B1 (+ A2[NN,K2]@B2) + bias ; Bt = [128][K1+K2] bf16
// Block: 256 thr = 4 waves x 16 rows = 64 rows; wave = 1 m-tile x 8 n-tiles.
// No LDS staging: B-frags are L2-broadcast (<=64 KB total), A-frags coalesce
// to 16 x 64B segments per load. Fused bias + BN column stats.
template <int K1, int K2, bool OUTBF>
__global__ __launch_bounds__(256) void gemm_mfma(const short* __restrict__ A1,
                                                 const short* __restrict__ A2,
                                                 const short* __restrict__ Bt,
                                                 const float* __restrict__ bias,
                                                 float* __restrict__ Cf,
                                                 unsigned short* __restrict__ Cb,
                                                 float* __restrict__ sums,
                                                 float* __restrict__ sumsq) {
  constexpr int KT = K1 + K2;
  __shared__ float lsum[128], lsq[128];
  int tid = threadIdx.x;
  if (tid < 128) { lsum[tid] = 0.f; lsq[tid] = 0.f; }
  __syncthreads();

  int lane = tid & 63;
  int w = tid >> 6;
  int r = lane & 15;  // A row-in-tile; C col
  int q = lane >> 4;  // k-quad; C row-quad
  int row = blockIdx.x * 64 + w * 16 + r;
  int rowc = row < NN ? row : NN - 1;  // clamp: garbage rows never stored

  f32x4 acc[8];
#pragma unroll
  for (int n = 0; n < 8; ++n) acc[n] = (f32x4){0.f, 0.f, 0.f, 0.f};

  {
    const short* Arow = A1 + (size_t)rowc * K1;
#pragma unroll
    for (int ks = 0; ks < K1; ks += 32) {
      short8 af = *(const short8*)(Arow + ks + q * 8);
#pragma unroll
      for (int n = 0; n < 8; ++n) {
        short8 bf = *(const short8*)(Bt + (n * 16 + r) * KT + ks + q * 8);
        acc[n] = __builtin_amdgcn_mfma_f32_16x16x32_bf16(af, bf, acc[n], 0, 0, 0);
      }
    }
  }
  if constexpr (K2 > 0) {
    const short* Arow = A2 + (size_t)rowc * K2;
#pragma unroll
    for (int ks = 0; ks < K2; ks += 32) {
      short8 af = *(const short8*)(Arow + ks + q * 8);
#pragma unroll
      for (int n = 0; n < 8; ++n) {
        short8 bf = *(const short8*)(Bt + (n * 16 + r) * KT + K1 + ks + q * 8);
        acc[n] = __builtin_amdgcn_mfma_f32_16x16x32_bf16(af, bf, acc[n], 0, 0, 0);
      }
    }
  }

  // epilogue: + bias, store, per-lane column partial stats
  float bias_r[8];
#pragma unroll
  for (int n = 0; n < 8; ++n) bias_r[n] = bias[n * 16 + r];
  float cs[8], cq[8];
#pragma unroll
  for (int n = 0; n < 8; ++n) { cs[n] = 0.f; cq[n] = 0.f; }
#pragma unroll
  for (int i = 0; i < 4; ++i) {
    int orow = blockIdx.x * 64 + w * 16 + q * 4 + i;
    if (orow < NN) {
#pragma unroll
      for (int n = 0; n < 8; ++n) {
        float v = acc[n][i] + bias_r[n];
        int col = n * 16 + r;
        if constexpr (OUTBF)
          Cb[(size_t)orow * 128 + col] = f2bf(v);
        else
          Cf[(size_t)orow * 128 + col] = v;
        cs[n] += v;
        cq[n] += v * v;
      }
    }
  }
#pragma unroll
  for (int n = 0; n < 8; ++n) {
    atomicAdd(&lsum[n * 16 + r], cs[n]);
    atomicAdd(&lsq[n * 16 + r], cq[n]);
  }
  __syncthreads();
  if (tid < 128) {
    atomicAdd(&sums[tid], lsum[tid]);
    atomicAdd(&sumsq[tid], lsq[tid]);
  }
}

// ---------------- BN finalize (in-block) + apply + ReLU, bf16 in-place ------
__global__ __launch_bounds__(256) void bn_apply_bf(unsigned* __restrict__ hb,
                                                   const float* __restrict__ sums,
                                                   const float* __restrict__ sumsq,
                                                   const float* __restrict__ gamma,
                                                   const float* __restrict__ beta) {
  __shared__ float sc[128], sh[128];
  int t = threadIdx.x;
  if (t < 128) {
    float mean = sums[t] * (1.0f / NN);
    float var = fmaxf(sumsq[t] * (1.0f / NN) - mean * mean, 0.f);
    float inv = rsqrtf(var + BN_EPS);
    float s = gamma[t] * inv;
    sc[t] = s;
    sh[t] = beta[t] - mean * s;
  }
  __syncthreads();
  int i = blockIdx.x * 256 + t;  // uint2 index; grid exact
  uint2 v = ((uint2*)hb)[i];
  int c = (i & 31) * 4;
  float f0 = fmaxf(fmaf(bflo(v.x), sc[c + 0], sh[c + 0]), 0.f);
  float f1 = fmaxf(fmaf(bfhi(v.x), sc[c + 1], sh[c + 1]), 0.f);
  float f2 = fmaxf(fmaf(bflo(v.y), sc[c + 2], sh[c + 2]), 0.f);
  float f3 = fmaxf(fmaf(bfhi(v.y), sc[c + 3], sh[c + 3]), 0.f);
  v.x = (unsigned)f2bf(f0) | ((unsigned)f2bf(f1) << 16);
  v.y = (unsigned)f2bf(f2) | ((unsigned)f2bf(f3) << 16);
  ((uint2*)hb)[i] = v;
}

// ---------------- BN finalize (in-block) + apply + ReLU, fp32 in-place ------
__global__ __launch_bounds__(256) void bn_apply_f32(float* __restrict__ out,
                                                    const float* __restrict__ sums,
                                                    const float* __restrict__ sumsq,
                                                    const float* __restrict__ gamma,
                                                    const float* __restrict__ beta) {
  __shared__ float sc[128], sh[128];
  int t = threadIdx.x;
  if (t < 128) {
    float mean = sums[t] * (1.0f / NN);
    float var = fmaxf(sumsq[t] * (1.0f / NN) - mean * mean, 0.f);
    float inv = rsqrtf(var + BN_EPS);
    float s = gamma[t] * inv;
    sc[t] = s;
    sh[t] = beta[t] - mean * s;
  }
  __syncthreads();
  int i4 = blockIdx.x * 256 + t;  // float4 index; grid exact
  float4 v = ((const float4*)out)[i4];
  int f = (i4 & 31) * 4;
  v.x = fmaxf(fmaf(v.x, sc[f + 0], sh[f + 0]), 0.f);
  v.y = fmaxf(fmaf(v.y, sc[f + 1], sh[f + 1]), 0.f);
  v.z = fmaxf(fmaf(v.z, sc[f + 2], sh[f + 2]), 0.f);
  v.w = fmaxf(fmaf(v.w, sc[f + 3], sh[f + 3]), 0.f);
  ((float4*)out)[i4] = v;
}

extern "C" void kernel_launch(void* const* d_in, const int* in_sizes, int n_in,
                              void* d_out, int out_size, void* d_ws, size_t ws_size,
                              hipStream_t stream) {
  const float* x   = (const float*)d_in[0];
  const int*   ei  = (const int*)d_in[1];
  const float* W1  = (const float*)d_in[2];
  const float* b1  = (const float*)d_in[3];
  const float* g1  = (const float*)d_in[4];
  const float* be1 = (const float*)d_in[5];
  const float* Wl  = (const float*)d_in[6];
  const float* bl  = (const float*)d_in[7];
  const float* Wr  = (const float*)d_in[8];
  const float* g2  = (const float*)d_in[9];
  const float* be2 = (const float*)d_in[10];
  const int* srcp = ei;
  const int* dstp = ei + NE;

  char* w = (char*)d_ws;
  auto alloc = [&](size_t bytes) {
    char* p = w;
    w += (bytes + 255) & ~(size_t)255;
    return p;
  };
  int*   cnt     = (int*)alloc((size_t)NN * 4);
  int*   fill    = (int*)alloc((size_t)NN * 4);
  int*   rowptr  = (int*)alloc((size_t)NN * 4);
  int*   partial = (int*)alloc(256 * 4);
  float* dis     = (float*)alloc((size_t)NN * 4);
  int*   csr     = (int*)alloc((size_t)NE * 4);
  unsigned short* xs     = (unsigned short*)alloc((size_t)NN * FIN * 2);
  unsigned short* xa     = (unsigned short*)alloc((size_t)NN * FIN * 2);
  unsigned short* hb     = (unsigned short*)alloc((size_t)NN * FHID * 2);
  unsigned*       neighb = (unsigned*)alloc((size_t)NN * FHID * 2);
  short* Bt1     = (short*)alloc(128 * 64 * 2);
  short* Bt2     = (short*)alloc(128 * 256 * 2);
  float* stats   = (float*)alloc(8 * 128 * 4);
  float* sums1 = stats,       *sumsq1 = stats + 128;
  float* sums2 = stats + 512, *sumsq2 = stats + 640;

  hipMemsetAsync(cnt, 0, (size_t)NN * 4, stream);
  hipMemsetAsync(fill, 0, (size_t)NN * 4, stream);
  hipMemsetAsync(stats, 0, 8 * 128 * 4, stream);

  int nbE = (NE + 255) / 256;
  int nbN = (NN + 255) / 256;  // 196 <= 256 (scan2 single-block limit)
  int nbG = (NN + 63) / 64;    // 782 MFMA blocks

  prep_B<<<160, 256, 0, stream>>>(W1, Wl, Wr, Bt1, Bt2);
  count_kernel<<<nbE, 256, 0, stream>>>(dstp, cnt);
  scan1<<<nbN, 256, 0, stream>>>(cnt, partial);
  scan2<<<1, 256, 0, stream>>>(partial, nbN);
  scan3<<<nbN, 256, 0, stream>>>(cnt, partial, rowptr, dis);
  fill_kernel<<<nbE, 256, 0, stream>>>(srcp, dstp, rowptr, fill, csr);
  scale_x<<<NN * FIN / 4 / 256, 256, 0, stream>>>(x, dis, (ushort4*)xs);

  // GCN: aggregate prescaled bf16 X, MFMA GEMM K=64 -> bf16 h
  gcn_agg<<<NN / 4, dim3(64, 4), 0, stream>>>(xs, csr, rowptr, cnt, dis, xa);
  gemm_mfma<64, 0, true><<<nbG, 256, 0, stream>>>(
      (const short*)xa, nullptr, Bt1, b1, nullptr, hb, sums1, sumsq1);
  bn_apply_bf<<<NN * FHID / 4 / 256, 256, 0, stream>>>((unsigned*)hb, sums1, sumsq1,
                                                       g1, be1);

  // SAGE: mean-agg bf16 h, fused K=256 MFMA GEMM -> fp32 d_out
  sage_agg<<<NN / 4, dim3(64, 4), 0, stream>>>((const unsigned*)hb, csr, rowptr, cnt,
                                               neighb);
  gemm_mfma<128, 128, false><<<nbG, 256, 0, stream>>>(
      (const short*)neighb, (const short*)hb, Bt2, bl, (float*)d_out, nullptr,
      sums2, sumsq2);
  bn_apply_f32<<<NN * FHID / 4 / 256, 256, 0, stream>>>((float*)d_out, sums2, sumsq2,
                                                        g2, be2);
}

// Round 5
// 300.491 us; speedup vs baseline: 1.0556x; 1.0556x over previous
//
#include <hip/hip_runtime.h>

#define NN 50000
#define NE 600000
#define FIN 64
#define FHID 128
#define BN_EPS 1e-5f

typedef __attribute__((ext_vector_type(8))) short short8;
typedef __attribute__((ext_vector_type(4))) float f32x4;

// ---- bf16 helpers (finite inputs; RNE) ----
__device__ __forceinline__ unsigned short f2bf(float f) {
  unsigned u = __float_as_uint(f);
  return (unsigned short)((u + 0x7FFFu + ((u >> 16) & 1u)) >> 16);
}
__device__ __forceinline__ float bfs(unsigned short u) {
  return __uint_as_float(((unsigned)u) << 16);
}
__device__ __forceinline__ float bflo(unsigned v) { return __uint_as_float(v << 16); }
__device__ __forceinline__ float bfhi(unsigned v) { return __uint_as_float(v & 0xFFFF0000u); }

// ---------------- edge counting ----------------
__global__ __launch_bounds__(256) void count_kernel(const int* __restrict__ dst,
                                                    int* __restrict__ cnt) {
  int e = blockIdx.x * 256 + threadIdx.x;
  if (e < NE) atomicAdd(&cnt[dst[e]], 1);
}

// ---------------- exclusive scan over cnt (3 kernels) ----------------
__global__ __launch_bounds__(256) void scan1(const int* __restrict__ cnt,
                                             int* __restrict__ partial) {
  int i = blockIdx.x * 256 + threadIdx.x;
  int v = (i < NN) ? cnt[i] : 0;
  __shared__ int sh[256];
  sh[threadIdx.x] = v;
  __syncthreads();
  for (int off = 128; off > 0; off >>= 1) {
    if (threadIdx.x < off) sh[threadIdx.x] += sh[threadIdx.x + off];
    __syncthreads();
  }
  if (threadIdx.x == 0) partial[blockIdx.x] = sh[0];
}

__global__ __launch_bounds__(256) void scan2(int* __restrict__ partial, int nb) {
  __shared__ int sh[256];
  int t = threadIdx.x;
  sh[t] = (t < nb) ? partial[t] : 0;
  __syncthreads();
  for (int off = 1; off < 256; off <<= 1) {
    int v = (t >= off) ? sh[t - off] : 0;
    __syncthreads();
    sh[t] += v;
    __syncthreads();
  }
  partial[t] = (t == 0) ? 0 : sh[t - 1];  // exclusive
}

__global__ __launch_bounds__(256) void scan3(const int* __restrict__ cnt,
                                             const int* __restrict__ partial,
                                             int* __restrict__ rowptr,
                                             float* __restrict__ dis) {
  int i = blockIdx.x * 256 + threadIdx.x;
  int t = threadIdx.x;
  int v = (i < NN) ? cnt[i] : 0;
  __shared__ int sh[256];
  sh[t] = v;
  __syncthreads();
  for (int off = 1; off < 256; off <<= 1) {
    int u = (t >= off) ? sh[t - off] : 0;
    __syncthreads();
    sh[t] += u;
    __syncthreads();
  }
  if (i < NN) {
    rowptr[i] = partial[blockIdx.x] + (sh[t] - v);
    dis[i] = rsqrtf((float)(v + 1));  // deg = indeg + 1 (self loop)
  }
}

// ---------------- CSR bucket fill ----------------
__global__ __launch_bounds__(256) void fill_kernel(const int* __restrict__ src,
                                                   const int* __restrict__ dst,
                                                   const int* __restrict__ rowptr,
                                                   int* __restrict__ fill,
                                                   int* __restrict__ csr_src) {
  int e = blockIdx.x * 256 + threadIdx.x;
  if (e < NE) {
    int d = dst[e];
    int p = atomicAdd(&fill[d], 1);
    csr_src[rowptr[d] + p] = src[e];
  }
}

// ---------------- xs = dis[node] * x  (fp32 -> bf16 prescale) ----------------
__global__ __launch_bounds__(256) void scale_x(const float* __restrict__ x,
                                               const float* __restrict__ dis,
                                               ushort4* __restrict__ xs) {
  int i = blockIdx.x * 256 + threadIdx.x;  // float4 index; grid exact (800000)
  float4 v = ((const float4*)x)[i];
  float d = dis[i >> 4];  // 16 float4 per 64-wide row
  xs[i] = make_ushort4(f2bf(v.x * d), f2bf(v.y * d), f2bf(v.z * d), f2bf(v.w * d));
}

// ---------------- weight prep: B^T in bf16, fragment row-major ---------------
// Bt1[128][64]  = W1^T ; Bt2[128][256] = [Wl;Wr]^T  (col-major over k)
__global__ __launch_bounds__(256) void prep_B(const float* __restrict__ W1,
                                              const float* __restrict__ Wl,
                                              const float* __restrict__ Wr,
                                              short* __restrict__ Bt1,
                                              short* __restrict__ Bt2) {
  int i = blockIdx.x * 256 + threadIdx.x;  // grid exact: 40960 threads
  if (i < 128 * 64) {
    int n = i >> 6, k = i & 63;
    Bt1[i] = (short)f2bf(W1[k * 128 + n]);
  } else {
    int j = i - 128 * 64;  // 128*256
    int n = j >> 8, k = j & 255;
    float wv = (k < 128) ? Wl[k * 128 + n] : Wr[(k - 128) * 128 + n];
    Bt2[j] = (short)f2bf(wv);
  }
}

// ---------------- GCN aggregation: xa = di*(xs[node] + sum_e xs[src]) -------
// one wave per node; 8/4/1-unrolled independent gathers for MLP
__global__ __launch_bounds__(256) void gcn_agg(const unsigned short* __restrict__ xs,
                                               const int* __restrict__ csr_src,
                                               const int* __restrict__ rowptr,
                                               const int* __restrict__ cnt,
                                               const float* __restrict__ dis,
                                               unsigned short* __restrict__ xa) {
  int node = blockIdx.x * 4 + threadIdx.y;
  int lane = threadIdx.x;
  float di = dis[node];
  float acc = bfs(xs[node * FIN + lane]);  // self loop: di * (di*x_node)
  int e = rowptr[node];
  int end = e + cnt[node];
  for (; e + 8 <= end; e += 8) {
    int s0 = csr_src[e + 0], s1 = csr_src[e + 1], s2 = csr_src[e + 2],
        s3 = csr_src[e + 3], s4 = csr_src[e + 4], s5 = csr_src[e + 5],
        s6 = csr_src[e + 6], s7 = csr_src[e + 7];
    float a0 = bfs(xs[s0 * FIN + lane]), a1 = bfs(xs[s1 * FIN + lane]);
    float a2 = bfs(xs[s2 * FIN + lane]), a3 = bfs(xs[s3 * FIN + lane]);
    float a4 = bfs(xs[s4 * FIN + lane]), a5 = bfs(xs[s5 * FIN + lane]);
    float a6 = bfs(xs[s6 * FIN + lane]), a7 = bfs(xs[s7 * FIN + lane]);
    acc += ((a0 + a1) + (a2 + a3)) + ((a4 + a5) + (a6 + a7));
  }
  for (; e + 4 <= end; e += 4) {
    int s0 = csr_src[e + 0], s1 = csr_src[e + 1], s2 = csr_src[e + 2],
        s3 = csr_src[e + 3];
    float a0 = bfs(xs[s0 * FIN + lane]), a1 = bfs(xs[s1 * FIN + lane]);
    float a2 = bfs(xs[s2 * FIN + lane]), a3 = bfs(xs[s3 * FIN + lane]);
    acc += (a0 + a1) + (a2 + a3);
  }
  for (; e < end; ++e) acc += bfs(xs[csr_src[e] * FIN + lane]);
  xa[node * FIN + lane] = f2bf(di * acc);
}

// ---------------- SAGE mean aggregation on bf16 h (128 feats) ---------------
__global__ __launch_bounds__(256) void sage_agg(const unsigned* __restrict__ hb,
                                                const int* __restrict__ csr_src,
                                                const int* __restrict__ rowptr,
                                                const int* __restrict__ cnt,
                                                unsigned* __restrict__ neighb) {
  int node = blockIdx.x * 4 + threadIdx.y;
  int lane = threadIdx.x;  // 2 feats per lane (1 uint = 2 bf16)
  float ax = 0.f, ay = 0.f;
  int num = cnt[node];
  int e = rowptr[node];
  int end = e + num;
  for (; e + 8 <= end; e += 8) {
    int s0 = csr_src[e + 0], s1 = csr_src[e + 1], s2 = csr_src[e + 2],
        s3 = csr_src[e + 3], s4 = csr_src[e + 4], s5 = csr_src[e + 5],
        s6 = csr_src[e + 6], s7 = csr_src[e + 7];
    unsigned v0 = hb[s0 * 64 + lane], v1 = hb[s1 * 64 + lane];
    unsigned v2 = hb[s2 * 64 + lane], v3 = hb[s3 * 64 + lane];
    unsigned v4 = hb[s4 * 64 + lane], v5 = hb[s5 * 64 + lane];
    unsigned v6 = hb[s6 * 64 + lane], v7 = hb[s7 * 64 + lane];
    ax += ((bflo(v0) + bflo(v1)) + (bflo(v2) + bflo(v3))) +
          ((bflo(v4) + bflo(v5)) + (bflo(v6) + bflo(v7)));
    ay += ((bfhi(v0) + bfhi(v1)) + (bfhi(v2) + bfhi(v3))) +
          ((bfhi(v4) + bfhi(v5)) + (bfhi(v6) + bfhi(v7)));
  }
  for (; e + 4 <= end; e += 4) {
    int s0 = csr_src[e + 0], s1 = csr_src[e + 1], s2 = csr_src[e + 2],
        s3 = csr_src[e + 3];
    unsigned v0 = hb[s0 * 64 + lane], v1 = hb[s1 * 64 + lane];
    unsigned v2 = hb[s2 * 64 + lane], v3 = hb[s3 * 64 + lane];
    ax += (bflo(v0) + bflo(v1)) + (bflo(v2) + bflo(v3));
    ay += (bfhi(v0) + bfhi(v1)) + (bfhi(v2) + bfhi(v3));
  }
  for (; e < end; ++e) {
    unsigned v = hb[csr_src[e] * 64 + lane];
    ax += bflo(v);
    ay += bfhi(v);
  }
  float inv = 1.0f / fmaxf((float)num, 1.0f);
  neighb[node * 64 + lane] =
      (unsigned)f2bf(ax * inv) | ((unsigned)f2bf(ay * inv) << 16);
}

// ---- one K-segment: vectorized-stage B chunk to LDS, then MFMA over it ----
// Bs row stride = K+8 shorts: 2-way bank alias only (free). Entered/exited
// with uniform barriers so segments can reuse the same LDS buffer.
template <int K>
__device__ __forceinline__ void seg_mfma(const short* __restrict__ Arow,
                                         const short* __restrict__ BtSeg, int KT,
                                         short* __restrict__ Bs, int tid, int r,
                                         int q, f32x4 (&acc)[8]) {
  constexpr int S = K + 8;
#pragma unroll
  for (int i = tid; i < 128 * K / 8; i += 256) {
    int c = i / (K / 8), j = i % (K / 8);
    *(short8*)(Bs + c * S + j * 8) = *(const short8*)(BtSeg + c * KT + j * 8);
  }
  __syncthreads();
#pragma unroll
  for (int ks = 0; ks < K; ks += 32) {
    short8 af = *(const short8*)(Arow + ks + q * 8);
#pragma unroll
    for (int n = 0; n < 8; ++n) {
      short8 bf = *(const short8*)(Bs + (n * 16 + r) * S + ks + q * 8);
      acc[n] = __builtin_amdgcn_mfma_f32_16x16x32_bf16(af, bf, acc[n], 0, 0, 0);
    }
  }
  __syncthreads();
}

// ---------------- MFMA bf16 GEMM: LDS B (K-chunked), global A --------------
// C[NN,128] = A1[NN,K1]@B1 (+ A2[NN,K2]@B2) + bias ; Bt = [128][K1+K2] bf16
// Block: 256 thr = 4 waves x 16 rows = 64 rows; wave = 1 m-tile x 8 n-tiles.
// LDS <= 34.8 KB -> 4 blocks/CU; grid 782 -> ~3 blocks/CU resident.
// Fused bias + BN column stats.
template <int K1, int K2, bool OUTBF>
__global__ __launch_bounds__(256) void gemm_mfma(const short* __restrict__ A1,
                                                 const short* __restrict__ A2,
                                                 const short* __restrict__ Bt,
                                                 const float* __restrict__ bias,
                                                 float* __restrict__ Cf,
                                                 unsigned short* __restrict__ Cb,
                                                 float* __restrict__ sums,
                                                 float* __restrict__ sumsq) {
  constexpr int KT = K1 + K2;
  __shared__ short Bs[128 * 136];  // covers max segment K=128 (stride 136)
  __shared__ float lsum[128], lsq[128];
  int tid = threadIdx.x;
  if (tid < 128) { lsum[tid] = 0.f; lsq[tid] = 0.f; }  // seg barrier covers init

  int lane = tid & 63;
  int w = tid >> 6;
  int r = lane & 15;  // A row-in-tile; C col
  int q = lane >> 4;  // k-quad; C row-quad
  int row = blockIdx.x * 64 + w * 16 + r;
  int rowc = row < NN ? row : NN - 1;  // clamp: garbage rows never stored

  f32x4 acc[8];
#pragma unroll
  for (int n = 0; n < 8; ++n) acc[n] = (f32x4){0.f, 0.f, 0.f, 0.f};

  seg_mfma<K1>(A1 + (size_t)rowc * K1, Bt, KT, Bs, tid, r, q, acc);
  if constexpr (K2 > 0)
    seg_mfma<K2>(A2 + (size_t)rowc * K2, Bt + K1, KT, Bs, tid, r, q, acc);

  // epilogue: + bias, store, per-lane column partial stats
  float bias_r[8];
#pragma unroll
  for (int n = 0; n < 8; ++n) bias_r[n] = bias[n * 16 + r];
  float cs[8], cq[8];
#pragma unroll
  for (int n = 0; n < 8; ++n) { cs[n] = 0.f; cq[n] = 0.f; }
#pragma unroll
  for (int i = 0; i < 4; ++i) {
    int orow = blockIdx.x * 64 + w * 16 + q * 4 + i;
    if (orow < NN) {
#pragma unroll
      for (int n = 0; n < 8; ++n) {
        float v = acc[n][i] + bias_r[n];
        int col = n * 16 + r;
        if constexpr (OUTBF)
          Cb[(size_t)orow * 128 + col] = f2bf(v);
        else
          Cf[(size_t)orow * 128 + col] = v;
        cs[n] += v;
        cq[n] += v * v;
      }
    }
  }
#pragma unroll
  for (int n = 0; n < 8; ++n) {
    atomicAdd(&lsum[n * 16 + r], cs[n]);
    atomicAdd(&lsq[n * 16 + r], cq[n]);
  }
  __syncthreads();
  if (tid < 128) {
    atomicAdd(&sums[tid], lsum[tid]);
    atomicAdd(&sumsq[tid], lsq[tid]);
  }
}

// ---------------- BN finalize (in-block) + apply + ReLU, bf16 in-place ------
__global__ __launch_bounds__(256) void bn_apply_bf(unsigned* __restrict__ hb,
                                                   const float* __restrict__ sums,
                                                   const float* __restrict__ sumsq,
                                                   const float* __restrict__ gamma,
                                                   const float* __restrict__ beta) {
  __shared__ float sc[128], sh[128];
  int t = threadIdx.x;
  if (t < 128) {
    float mean = sums[t] * (1.0f / NN);
    float var = fmaxf(sumsq[t] * (1.0f / NN) - mean * mean, 0.f);
    float inv = rsqrtf(var + BN_EPS);
    float s = gamma[t] * inv;
    sc[t] = s;
    sh[t] = beta[t] - mean * s;
  }
  __syncthreads();
  int i = blockIdx.x * 256 + t;  // uint2 index; grid exact
  uint2 v = ((uint2*)hb)[i];
  int c = (i & 31) * 4;
  float f0 = fmaxf(fmaf(bflo(v.x), sc[c + 0], sh[c + 0]), 0.f);
  float f1 = fmaxf(fmaf(bfhi(v.x), sc[c + 1], sh[c + 1]), 0.f);
  float f2 = fmaxf(fmaf(bflo(v.y), sc[c + 2], sh[c + 2]), 0.f);
  float f3 = fmaxf(fmaf(bfhi(v.y), sc[c + 3], sh[c + 3]), 0.f);
  v.x = (unsigned)f2bf(f0) | ((unsigned)f2bf(f1) << 16);
  v.y = (unsigned)f2bf(f2) | ((unsigned)f2bf(f3) << 16);
  ((uint2*)hb)[i] = v;
}

// ---------------- BN finalize (in-block) + apply + ReLU, fp32 in-place ------
__global__ __launch_bounds__(256) void bn_apply_f32(float* __restrict__ out,
                                                    const float* __restrict__ sums,
                                                    const float* __restrict__ sumsq,
                                                    const float* __restrict__ gamma,
                                                    const float* __restrict__ beta) {
  __shared__ float sc[128], sh[128];
  int t = threadIdx.x;
  if (t < 128) {
    float mean = sums[t] * (1.0f / NN);
    float var = fmaxf(sumsq[t] * (1.0f / NN) - mean * mean, 0.f);
    float inv = rsqrtf(var + BN_EPS);
    float s = gamma[t] * inv;
    sc[t] = s;
    sh[t] = beta[t] - mean * s;
  }
  __syncthreads();
  int i4 = blockIdx.x * 256 + t;  // float4 index; grid exact
  float4 v = ((const float4*)out)[i4];
  int f = (i4 & 31) * 4;
  v.x = fmaxf(fmaf(v.x, sc[f + 0], sh[f + 0]), 0.f);
  v.y = fmaxf(fmaf(v.y, sc[f + 1], sh[f + 1]), 0.f);
  v.z = fmaxf(fmaf(v.z, sc[f + 2], sh[f + 2]), 0.f);
  v.w = fmaxf(fmaf(v.w, sc[f + 3], sh[f + 3]), 0.f);
  ((float4*)out)[i4] = v;
}

extern "C" void kernel_launch(void* const* d_in, const int* in_sizes, int n_in,
                              void* d_out, int out_size, void* d_ws, size_t ws_size,
                              hipStream_t stream) {
  const float* x   = (const float*)d_in[0];
  const int*   ei  = (const int*)d_in[1];
  const float* W1  = (const float*)d_in[2];
  const float* b1  = (const float*)d_in[3];
  const float* g1  = (const float*)d_in[4];
  const float* be1 = (const float*)d_in[5];
  const float* Wl  = (const float*)d_in[6];
  const float* bl  = (const float*)d_in[7];
  const float* Wr  = (const float*)d_in[8];
  const float* g2  = (const float*)d_in[9];
  const float* be2 = (const float*)d_in[10];
  const int* srcp = ei;
  const int* dstp = ei + NE;

  char* w = (char*)d_ws;
  auto alloc = [&](size_t bytes) {
    char* p = w;
    w += (bytes + 255) & ~(size_t)255;
    return p;
  };
  int*   cnt     = (int*)alloc((size_t)NN * 4);
  int*   fill    = (int*)alloc((size_t)NN * 4);
  int*   rowptr  = (int*)alloc((size_t)NN * 4);
  int*   partial = (int*)alloc(256 * 4);
  float* dis     = (float*)alloc((size_t)NN * 4);
  int*   csr     = (int*)alloc((size_t)NE * 4);
  unsigned short* xs     = (unsigned short*)alloc((size_t)NN * FIN * 2);
  unsigned short* xa     = (unsigned short*)alloc((size_t)NN * FIN * 2);
  unsigned short* hb     = (unsigned short*)alloc((size_t)NN * FHID * 2);
  unsigned*       neighb = (unsigned*)alloc((size_t)NN * FHID * 2);
  short* Bt1     = (short*)alloc(128 * 64 * 2);
  short* Bt2     = (short*)alloc(128 * 256 * 2);
  float* stats   = (float*)alloc(8 * 128 * 4);
  float* sums1 = stats,       *sumsq1 = stats + 128;
  float* sums2 = stats + 512, *sumsq2 = stats + 640;

  hipMemsetAsync(cnt, 0, (size_t)NN * 4, stream);
  hipMemsetAsync(fill, 0, (size_t)NN * 4, stream);
  hipMemsetAsync(stats, 0, 8 * 128 * 4, stream);

  int nbE = (NE + 255) / 256;
  int nbN = (NN + 255) / 256;  // 196 <= 256 (scan2 single-block limit)
  int nbG = (NN + 63) / 64;    // 782 MFMA blocks

  prep_B<<<160, 256, 0, stream>>>(W1, Wl, Wr, Bt1, Bt2);
  count_kernel<<<nbE, 256, 0, stream>>>(dstp, cnt);
  scan1<<<nbN, 256, 0, stream>>>(cnt, partial);
  scan2<<<1, 256, 0, stream>>>(partial, nbN);
  scan3<<<nbN, 256, 0, stream>>>(cnt, partial, rowptr, dis);
  fill_kernel<<<nbE, 256, 0, stream>>>(srcp, dstp, rowptr, fill, csr);
  scale_x<<<NN * FIN / 4 / 256, 256, 0, stream>>>(x, dis, (ushort4*)xs);

  // GCN: aggregate prescaled bf16 X, MFMA GEMM K=64 -> bf16 h
  gcn_agg<<<NN / 4, dim3(64, 4), 0, stream>>>(xs, csr, rowptr, cnt, dis, xa);
  gemm_mfma<64, 0, true><<<nbG, 256, 0, stream>>>(
      (const short*)xa, nullptr, Bt1, b1, nullptr, hb, sums1, sumsq1);
  bn_apply_bf<<<NN * FHID / 4 / 256, 256, 0, stream>>>((unsigned*)hb, sums1, sumsq1,
                                                       g1, be1);

  // SAGE: mean-agg bf16 h, fused K=256 MFMA GEMM -> fp32 d_out
  sage_agg<<<NN / 4, dim3(64, 4), 0, stream>>>((const unsigned*)hb, csr, rowptr, cnt,
                                               neighb);
  gemm_mfma<128, 128, false><<<nbG, 256, 0, stream>>>(
      (const short*)neighb, (const short*)hb, Bt2, bl, (float*)d_out, nullptr,
      sums2, sumsq2);
  bn_apply_f32<<<NN * FHID / 4 / 256, 256, 0, stream>>>((float*)d_out, sums2, sumsq2,
                                                        g2, be2);
}

// Round 6
// 287.623 us; speedup vs baseline: 1.1028x; 1.0447x over previous
//
#include <hip/hip_runtime.h>

#define NN 50000
#define NE 600000
#define FIN 64
#define FHID 128
#define BN_EPS 1e-5f

typedef __attribute__((ext_vector_type(8))) short short8;
typedef __attribute__((ext_vector_type(4))) float f32x4;

// ---- bf16 helpers (finite inputs; RNE) ----
__device__ __forceinline__ unsigned short f2bf(float f) {
  unsigned u = __float_as_uint(f);
  return (unsigned short)((u + 0x7FFFu + ((u >> 16) & 1u)) >> 16);
}
__device__ __forceinline__ float bfs(unsigned short u) {
  return __uint_as_float(((unsigned)u) << 16);
}
__device__ __forceinline__ float bflo(unsigned v) { return __uint_as_float(v << 16); }
__device__ __forceinline__ float bfhi(unsigned v) { return __uint_as_float(v & 0xFFFF0000u); }

// ---------------- edge counting ----------------
__global__ __launch_bounds__(256) void count_kernel(const int* __restrict__ dst,
                                                    int* __restrict__ cnt) {
  int e = blockIdx.x * 256 + threadIdx.x;
  if (e < NE) atomicAdd(&cnt[dst[e]], 1);
}

// ---------------- exclusive scan over cnt (3 kernels) ----------------
__global__ __launch_bounds__(256) void scan1(const int* __restrict__ cnt,
                                             int* __restrict__ partial) {
  int i = blockIdx.x * 256 + threadIdx.x;
  int v = (i < NN) ? cnt[i] : 0;
  __shared__ int sh[256];
  sh[threadIdx.x] = v;
  __syncthreads();
  for (int off = 128; off > 0; off >>= 1) {
    if (threadIdx.x < off) sh[threadIdx.x] += sh[threadIdx.x + off];
    __syncthreads();
  }
  if (threadIdx.x == 0) partial[blockIdx.x] = sh[0];
}

__global__ __launch_bounds__(256) void scan2(int* __restrict__ partial, int nb) {
  __shared__ int sh[256];
  int t = threadIdx.x;
  sh[t] = (t < nb) ? partial[t] : 0;
  __syncthreads();
  for (int off = 1; off < 256; off <<= 1) {
    int v = (t >= off) ? sh[t - off] : 0;
    __syncthreads();
    sh[t] += v;
    __syncthreads();
  }
  partial[t] = (t == 0) ? 0 : sh[t - 1];  // exclusive
}

__global__ __launch_bounds__(256) void scan3(const int* __restrict__ cnt,
                                             const int* __restrict__ partial,
                                             int* __restrict__ rowptr,
                                             float* __restrict__ dis) {
  int i = blockIdx.x * 256 + threadIdx.x;
  int t = threadIdx.x;
  int v = (i < NN) ? cnt[i] : 0;
  __shared__ int sh[256];
  sh[t] = v;
  __syncthreads();
  for (int off = 1; off < 256; off <<= 1) {
    int u = (t >= off) ? sh[t - off] : 0;
    __syncthreads();
    sh[t] += u;
    __syncthreads();
  }
  if (i < NN) {
    rowptr[i] = partial[blockIdx.x] + (sh[t] - v);
    dis[i] = rsqrtf((float)(v + 1));  // deg = indeg + 1 (self loop)
  }
}

// ---------------- CSR bucket fill ----------------
__global__ __launch_bounds__(256) void fill_kernel(const int* __restrict__ src,
                                                   const int* __restrict__ dst,
                                                   const int* __restrict__ rowptr,
                                                   int* __restrict__ fill,
                                                   int* __restrict__ csr_src) {
  int e = blockIdx.x * 256 + threadIdx.x;
  if (e < NE) {
    int d = dst[e];
    int p = atomicAdd(&fill[d], 1);
    csr_src[rowptr[d] + p] = src[e];
  }
}

// ---------------- xs = dis[node] * x  (fp32 -> bf16 prescale) ----------------
__global__ __launch_bounds__(256) void scale_x(const float* __restrict__ x,
                                               const float* __restrict__ dis,
                                               ushort4* __restrict__ xs) {
  int i = blockIdx.x * 256 + threadIdx.x;  // float4 index; grid exact (800000)
  float4 v = ((const float4*)x)[i];
  float d = dis[i >> 4];  // 16 float4 per 64-wide row
  xs[i] = make_ushort4(f2bf(v.x * d), f2bf(v.y * d), f2bf(v.z * d), f2bf(v.w * d));
}

// ---------------- weight prep: B^T in bf16, fragment row-major ---------------
// Bt1[128][64]  = W1^T ; Bt2[128][256] = [Wl;Wr]^T  (col-major over k)
__global__ __launch_bounds__(256) void prep_B(const float* __restrict__ W1,
                                              const float* __restrict__ Wl,
                                              const float* __restrict__ Wr,
                                              short* __restrict__ Bt1,
                                              short* __restrict__ Bt2) {
  int i = blockIdx.x * 256 + threadIdx.x;  // grid exact: 40960 threads
  if (i < 128 * 64) {
    int n = i >> 6, k = i & 63;
    Bt1[i] = (short)f2bf(W1[k * 128 + n]);
  } else {
    int j = i - 128 * 64;  // 128*256
    int n = j >> 8, k = j & 255;
    float wv = (k < 128) ? Wl[k * 128 + n] : Wr[(k - 128) * 128 + n];
    Bt2[j] = (short)f2bf(wv);
  }
}

// ---------------- GCN aggregation: xa = di*(xs[node] + sum_e xs[src]) -------
// 32 lanes x uint (2 feats) per node, 8 nodes/block; 8/4/1-unrolled gathers
__global__ __launch_bounds__(256) void gcn_agg(const unsigned* __restrict__ xs,
                                               const int* __restrict__ csr_src,
                                               const int* __restrict__ rowptr,
                                               const int* __restrict__ cnt,
                                               const float* __restrict__ dis,
                                               unsigned* __restrict__ xa) {
  int node = blockIdx.x * 8 + threadIdx.y;
  int lane = threadIdx.x;  // 0..31, 2 feats per lane
  float di = dis[node];
  unsigned sv = xs[node * 32 + lane];
  float ax = bflo(sv), ay = bfhi(sv);  // self loop: di * (di*x_node)
  int e = rowptr[node];
  int end = e + cnt[node];
  for (; e + 8 <= end; e += 8) {
    int s0 = csr_src[e + 0], s1 = csr_src[e + 1], s2 = csr_src[e + 2],
        s3 = csr_src[e + 3], s4 = csr_src[e + 4], s5 = csr_src[e + 5],
        s6 = csr_src[e + 6], s7 = csr_src[e + 7];
    unsigned v0 = xs[s0 * 32 + lane], v1 = xs[s1 * 32 + lane];
    unsigned v2 = xs[s2 * 32 + lane], v3 = xs[s3 * 32 + lane];
    unsigned v4 = xs[s4 * 32 + lane], v5 = xs[s5 * 32 + lane];
    unsigned v6 = xs[s6 * 32 + lane], v7 = xs[s7 * 32 + lane];
    ax += ((bflo(v0) + bflo(v1)) + (bflo(v2) + bflo(v3))) +
          ((bflo(v4) + bflo(v5)) + (bflo(v6) + bflo(v7)));
    ay += ((bfhi(v0) + bfhi(v1)) + (bfhi(v2) + bfhi(v3))) +
          ((bfhi(v4) + bfhi(v5)) + (bfhi(v6) + bfhi(v7)));
  }
  for (; e + 4 <= end; e += 4) {
    int s0 = csr_src[e + 0], s1 = csr_src[e + 1], s2 = csr_src[e + 2],
        s3 = csr_src[e + 3];
    unsigned v0 = xs[s0 * 32 + lane], v1 = xs[s1 * 32 + lane];
    unsigned v2 = xs[s2 * 32 + lane], v3 = xs[s3 * 32 + lane];
    ax += (bflo(v0) + bflo(v1)) + (bflo(v2) + bflo(v3));
    ay += (bfhi(v0) + bfhi(v1)) + (bfhi(v2) + bfhi(v3));
  }
  for (; e < end; ++e) {
    unsigned v = xs[csr_src[e] * 32 + lane];
    ax += bflo(v);
    ay += bfhi(v);
  }
  xa[node * 32 + lane] = (unsigned)f2bf(di * ax) | ((unsigned)f2bf(di * ay) << 16);
}

// ---------------- SAGE mean aggregation on bf16 h (128 feats) ---------------
// 32 lanes x uint2 (4 feats) per node, 8 nodes/block
__global__ __launch_bounds__(256) void sage_agg(const uint2* __restrict__ hb,
                                                const int* __restrict__ csr_src,
                                                const int* __restrict__ rowptr,
                                                const int* __restrict__ cnt,
                                                uint2* __restrict__ neighb) {
  int node = blockIdx.x * 8 + threadIdx.y;
  int lane = threadIdx.x;  // 0..31, 4 feats per lane
  float a0 = 0.f, a1 = 0.f, a2 = 0.f, a3 = 0.f;
  int num = cnt[node];
  int e = rowptr[node];
  int end = e + num;
  for (; e + 8 <= end; e += 8) {
    int s0 = csr_src[e + 0], s1 = csr_src[e + 1], s2 = csr_src[e + 2],
        s3 = csr_src[e + 3], s4 = csr_src[e + 4], s5 = csr_src[e + 5],
        s6 = csr_src[e + 6], s7 = csr_src[e + 7];
    uint2 v0 = hb[s0 * 32 + lane], v1 = hb[s1 * 32 + lane];
    uint2 v2 = hb[s2 * 32 + lane], v3 = hb[s3 * 32 + lane];
    uint2 v4 = hb[s4 * 32 + lane], v5 = hb[s5 * 32 + lane];
    uint2 v6 = hb[s6 * 32 + lane], v7 = hb[s7 * 32 + lane];
    a0 += ((bflo(v0.x) + bflo(v1.x)) + (bflo(v2.x) + bflo(v3.x))) +
          ((bflo(v4.x) + bflo(v5.x)) + (bflo(v6.x) + bflo(v7.x)));
    a1 += ((bfhi(v0.x) + bfhi(v1.x)) + (bfhi(v2.x) + bfhi(v3.x))) +
          ((bfhi(v4.x) + bfhi(v5.x)) + (bfhi(v6.x) + bfhi(v7.x)));
    a2 += ((bflo(v0.y) + bflo(v1.y)) + (bflo(v2.y) + bflo(v3.y))) +
          ((bflo(v4.y) + bflo(v5.y)) + (bflo(v6.y) + bflo(v7.y)));
    a3 += ((bfhi(v0.y) + bfhi(v1.y)) + (bfhi(v2.y) + bfhi(v3.y))) +
          ((bfhi(v4.y) + bfhi(v5.y)) + (bfhi(v6.y) + bfhi(v7.y)));
  }
  for (; e + 4 <= end; e += 4) {
    int s0 = csr_src[e + 0], s1 = csr_src[e + 1], s2 = csr_src[e + 2],
        s3 = csr_src[e + 3];
    uint2 v0 = hb[s0 * 32 + lane], v1 = hb[s1 * 32 + lane];
    uint2 v2 = hb[s2 * 32 + lane], v3 = hb[s3 * 32 + lane];
    a0 += (bflo(v0.x) + bflo(v1.x)) + (bflo(v2.x) + bflo(v3.x));
    a1 += (bfhi(v0.x) + bfhi(v1.x)) + (bfhi(v2.x) + bfhi(v3.x));
    a2 += (bflo(v0.y) + bflo(v1.y)) + (bflo(v2.y) + bflo(v3.y));
    a3 += (bfhi(v0.y) + bfhi(v1.y)) + (bfhi(v2.y) + bfhi(v3.y));
  }
  for (; e < end; ++e) {
    uint2 v = hb[csr_src[e] * 32 + lane];
    a0 += bflo(v.x);
    a1 += bfhi(v.x);
    a2 += bflo(v.y);
    a3 += bfhi(v.y);
  }
  float inv = 1.0f / fmaxf((float)num, 1.0f);
  uint2 o;
  o.x = (unsigned)f2bf(a0 * inv) | ((unsigned)f2bf(a1 * inv) << 16);
  o.y = (unsigned)f2bf(a2 * inv) | ((unsigned)f2bf(a3 * inv) << 16);
  neighb[node * 32 + lane] = o;
}

// ---------------- MFMA bf16 GEMM: B in registers, A streamed, no barriers ---
// C[NN,128] = A1[NN,K1]@B1 (+ A2[NN,K2]@B2) + bias ; Bt = [128][K1+K2] bf16
// Block: 256 thr = 4 waves, 64 rows. Wave = 4 m-tiles x 2 n-tiles; B-frags
// for the wave's 2 n-tiles x full K live in registers (<=64 VGPR). K-loop is
// barrier-free: 4 independent coalesced A loads + 8 MFMAs per k-step.
// Fused bias + BN column stats (shfl-reduce, 1 KB LDS, 256 atomics/block).
template <int K1, int K2, bool OUTBF>
__global__ __launch_bounds__(256) void gemm_mfma(const short* __restrict__ A1,
                                                 const short* __restrict__ A2,
                                                 const short* __restrict__ Bt,
                                                 const float* __restrict__ bias,
                                                 float* __restrict__ Cf,
                                                 unsigned short* __restrict__ Cb,
                                                 float* __restrict__ sums,
                                                 float* __restrict__ sumsq) {
  constexpr int KT = K1 + K2;
  constexpr int NK = KT / 32;  // total k-steps
  __shared__ float lsum[128], lsq[128];
  int tid = threadIdx.x;
  int lane = tid & 63;
  int w = tid >> 6;   // wave id -> n-tile pair
  int r = lane & 15;  // A/B row-in-tile; C col
  int q = lane >> 4;  // k-quad; C row-quad
  int row_base = blockIdx.x * 64;

  // B-frags for this wave's 2 n-tiles, all k-steps (registers)
  short8 bfr[2][NK];
#pragma unroll
  for (int nn = 0; nn < 2; ++nn) {
    const short* bp = Bt + (size_t)((w * 2 + nn) * 16 + r) * KT + q * 8;
#pragma unroll
    for (int kk = 0; kk < NK; ++kk) bfr[nn][kk] = *(const short8*)(bp + kk * 32);
  }

  int rows[4];
#pragma unroll
  for (int m = 0; m < 4; ++m) {
    int rr = row_base + m * 16 + r;
    rows[m] = rr < NN ? rr : NN - 1;  // clamp: garbage rows never stored
  }

  f32x4 acc[4][2];
#pragma unroll
  for (int m = 0; m < 4; ++m)
#pragma unroll
    for (int nn = 0; nn < 2; ++nn) acc[m][nn] = (f32x4){0.f, 0.f, 0.f, 0.f};

#pragma unroll
  for (int kk = 0; kk < K1 / 32; ++kk) {
    short8 af[4];
#pragma unroll
    for (int m = 0; m < 4; ++m)
      af[m] = *(const short8*)(A1 + (size_t)rows[m] * K1 + kk * 32 + q * 8);
#pragma unroll
    for (int m = 0; m < 4; ++m)
#pragma unroll
      for (int nn = 0; nn < 2; ++nn)
        acc[m][nn] =
            __builtin_amdgcn_mfma_f32_16x16x32_bf16(af[m], bfr[nn][kk], acc[m][nn], 0, 0, 0);
  }
  if constexpr (K2 > 0) {
#pragma unroll
    for (int kk = 0; kk < K2 / 32; ++kk) {
      short8 af[4];
#pragma unroll
      for (int m = 0; m < 4; ++m)
        af[m] = *(const short8*)(A2 + (size_t)rows[m] * K2 + kk * 32 + q * 8);
#pragma unroll
      for (int m = 0; m < 4; ++m)
#pragma unroll
        for (int nn = 0; nn < 2; ++nn)
          acc[m][nn] = __builtin_amdgcn_mfma_f32_16x16x32_bf16(
              af[m], bfr[nn][K1 / 32 + kk], acc[m][nn], 0, 0, 0);
    }
  }

  // epilogue: + bias, store, column stats
  float bias_r[2];
#pragma unroll
  for (int nn = 0; nn < 2; ++nn) bias_r[nn] = bias[(w * 2 + nn) * 16 + r];
  float cs[2] = {0.f, 0.f}, cq[2] = {0.f, 0.f};
#pragma unroll
  for (int m = 0; m < 4; ++m)
#pragma unroll
    for (int i = 0; i < 4; ++i) {
      int orow = row_base + m * 16 + q * 4 + i;
      if (orow < NN) {
#pragma unroll
        for (int nn = 0; nn < 2; ++nn) {
          float v = acc[m][nn][i] + bias_r[nn];
          int col = (w * 2 + nn) * 16 + r;
          if constexpr (OUTBF)
            Cb[(size_t)orow * 128 + col] = f2bf(v);
          else
            Cf[(size_t)orow * 128 + col] = v;
          cs[nn] += v;
          cq[nn] += v * v;
        }
      }
    }
  // reduce across the 4 q-groups (lanes differing in bits 4,5)
#pragma unroll
  for (int nn = 0; nn < 2; ++nn) {
    cs[nn] += __shfl_xor(cs[nn], 16);
    cs[nn] += __shfl_xor(cs[nn], 32);
    cq[nn] += __shfl_xor(cq[nn], 16);
    cq[nn] += __shfl_xor(cq[nn], 32);
  }
  if (q == 0) {  // lanes 0..15: each wave owns cols [w*32, w*32+32)
#pragma unroll
    for (int nn = 0; nn < 2; ++nn) {
      int col = (w * 2 + nn) * 16 + r;
      lsum[col] = cs[nn];
      lsq[col] = cq[nn];
    }
  }
  __syncthreads();
  if (tid < 128) {
    atomicAdd(&sums[tid], lsum[tid]);
    atomicAdd(&sumsq[tid], lsq[tid]);
  }
}

// ---------------- BN finalize (in-block) + apply + ReLU, bf16 in-place ------
__global__ __launch_bounds__(256) void bn_apply_bf(unsigned* __restrict__ hb,
                                                   const float* __restrict__ sums,
                                                   const float* __restrict__ sumsq,
                                                   const float* __restrict__ gamma,
                                                   const float* __restrict__ beta) {
  __shared__ float sc[128], sh[128];
  int t = threadIdx.x;
  if (t < 128) {
    float mean = sums[t] * (1.0f / NN);
    float var = fmaxf(sumsq[t] * (1.0f / NN) - mean * mean, 0.f);
    float inv = rsqrtf(var + BN_EPS);
    float s = gamma[t] * inv;
    sc[t] = s;
    sh[t] = beta[t] - mean * s;
  }
  __syncthreads();
  int i = blockIdx.x * 256 + t;  // uint2 index; grid exact
  uint2 v = ((uint2*)hb)[i];
  int c = (i & 31) * 4;
  float f0 = fmaxf(fmaf(bflo(v.x), sc[c + 0], sh[c + 0]), 0.f);
  float f1 = fmaxf(fmaf(bfhi(v.x), sc[c + 1], sh[c + 1]), 0.f);
  float f2 = fmaxf(fmaf(bflo(v.y), sc[c + 2], sh[c + 2]), 0.f);
  float f3 = fmaxf(fmaf(bfhi(v.y), sc[c + 3], sh[c + 3]), 0.f);
  v.x = (unsigned)f2bf(f0) | ((unsigned)f2bf(f1) << 16);
  v.y = (unsigned)f2bf(f2) | ((unsigned)f2bf(f3) << 16);
  ((uint2*)hb)[i] = v;
}

// ---------------- BN finalize (in-block) + apply + ReLU, fp32 in-place ------
__global__ __launch_bounds__(256) void bn_apply_f32(float* __restrict__ out,
                                                    const float* __restrict__ sums,
                                                    const float* __restrict__ sumsq,
                                                    const float* __restrict__ gamma,
                                                    const float* __restrict__ beta) {
  __shared__ float sc[128], sh[128];
  int t = threadIdx.x;
  if (t < 128) {
    float mean = sums[t] * (1.0f / NN);
    float var = fmaxf(sumsq[t] * (1.0f / NN) - mean * mean, 0.f);
    float inv = rsqrtf(var + BN_EPS);
    float s = gamma[t] * inv;
    sc[t] = s;
    sh[t] = beta[t] - mean * s;
  }
  __syncthreads();
  int i4 = blockIdx.x * 256 + t;  // float4 index; grid exact
  float4 v = ((const float4*)out)[i4];
  int f = (i4 & 31) * 4;
  v.x = fmaxf(fmaf(v.x, sc[f + 0], sh[f + 0]), 0.f);
  v.y = fmaxf(fmaf(v.y, sc[f + 1], sh[f + 1]), 0.f);
  v.z = fmaxf(fmaf(v.z, sc[f + 2], sh[f + 2]), 0.f);
  v.w = fmaxf(fmaf(v.w, sc[f + 3], sh[f + 3]), 0.f);
  ((float4*)out)[i4] = v;
}

extern "C" void kernel_launch(void* const* d_in, const int* in_sizes, int n_in,
                              void* d_out, int out_size, void* d_ws, size_t ws_size,
                              hipStream_t stream) {
  const float* x   = (const float*)d_in[0];
  const int*   ei  = (const int*)d_in[1];
  const float* W1  = (const float*)d_in[2];
  const float* b1  = (const float*)d_in[3];
  const float* g1  = (const float*)d_in[4];
  const float* be1 = (const float*)d_in[5];
  const float* Wl  = (const float*)d_in[6];
  const float* bl  = (const float*)d_in[7];
  const float* Wr  = (const float*)d_in[8];
  const float* g2  = (const float*)d_in[9];
  const float* be2 = (const float*)d_in[10];
  const int* srcp = ei;
  const int* dstp = ei + NE;

  char* w = (char*)d_ws;
  auto alloc = [&](size_t bytes) {
    char* p = w;
    w += (bytes + 255) & ~(size_t)255;
    return p;
  };
  int*   cnt     = (int*)alloc((size_t)NN * 4);
  int*   fill    = (int*)alloc((size_t)NN * 4);
  int*   rowptr  = (int*)alloc((size_t)NN * 4);
  int*   partial = (int*)alloc(256 * 4);
  float* dis     = (float*)alloc((size_t)NN * 4);
  int*   csr     = (int*)alloc((size_t)NE * 4);
  unsigned short* xs     = (unsigned short*)alloc((size_t)NN * FIN * 2);
  unsigned short* xa     = (unsigned short*)alloc((size_t)NN * FIN * 2);
  unsigned short* hb     = (unsigned short*)alloc((size_t)NN * FHID * 2);
  unsigned*       neighb = (unsigned*)alloc((size_t)NN * FHID * 2);
  short* Bt1     = (short*)alloc(128 * 64 * 2);
  short* Bt2     = (short*)alloc(128 * 256 * 2);
  float* stats   = (float*)alloc(8 * 128 * 4);
  float* sums1 = stats,       *sumsq1 = stats + 128;
  float* sums2 = stats + 512, *sumsq2 = stats + 640;

  hipMemsetAsync(cnt, 0, (size_t)NN * 4, stream);
  hipMemsetAsync(fill, 0, (size_t)NN * 4, stream);
  hipMemsetAsync(stats, 0, 8 * 128 * 4, stream);

  int nbE = (NE + 255) / 256;
  int nbN = (NN + 255) / 256;  // 196 <= 256 (scan2 single-block limit)
  int nbG = (NN + 63) / 64;    // 782 MFMA blocks

  prep_B<<<160, 256, 0, stream>>>(W1, Wl, Wr, Bt1, Bt2);
  count_kernel<<<nbE, 256, 0, stream>>>(dstp, cnt);
  scan1<<<nbN, 256, 0, stream>>>(cnt, partial);
  scan2<<<1, 256, 0, stream>>>(partial, nbN);
  scan3<<<nbN, 256, 0, stream>>>(cnt, partial, rowptr, dis);
  fill_kernel<<<nbE, 256, 0, stream>>>(srcp, dstp, rowptr, fill, csr);
  scale_x<<<NN * FIN / 4 / 256, 256, 0, stream>>>(x, dis, (ushort4*)xs);

  // GCN: aggregate prescaled bf16 X, MFMA GEMM K=64 -> bf16 h
  gcn_agg<<<NN / 8, dim3(32, 8), 0, stream>>>((const unsigned*)xs, csr, rowptr, cnt,
                                              dis, (unsigned*)xa);
  gemm_mfma<64, 0, true><<<nbG, 256, 0, stream>>>(
      (const short*)xa, nullptr, Bt1, b1, nullptr, hb, sums1, sumsq1);
  bn_apply_bf<<<NN * FHID / 4 / 256, 256, 0, stream>>>((unsigned*)hb, sums1, sumsq1,
                                                       g1, be1);

  // SAGE: mean-agg bf16 h, fused K=256 MFMA GEMM -> fp32 d_out
  sage_agg<<<NN / 8, dim3(32, 8), 0, stream>>>((const uint2*)hb, csr, rowptr, cnt,
                                               (uint2*)neighb);
  gemm_mfma<128, 128, false><<<nbG, 256, 0, stream>>>(
      (const short*)neighb, (const short*)hb, Bt2, bl, (float*)d_out, nullptr,
      sums2, sumsq2);
  bn_apply_f32<<<NN * FHID / 4 / 256, 256, 0, stream>>>((float*)d_out, sums2, sumsq2,
                                                        g2, be2);
}

// Round 7
// 281.003 us; speedup vs baseline: 1.1288x; 1.0236x over previous
//
#include <hip/hip_runtime.h>

#define NN 50000
#define NE 600000
#define FIN 64
#define FHID 128
#define BN_EPS 1e-5f

typedef __attribute__((ext_vector_type(8))) short short8;
typedef __attribute__((ext_vector_type(4))) float f32x4;

// ---- bf16 helpers (finite inputs; RNE) ----
__device__ __forceinline__ unsigned short f2bf(float f) {
  unsigned u = __float_as_uint(f);
  return (unsigned short)((u + 0x7FFFu + ((u >> 16) & 1u)) >> 16);
}
__device__ __forceinline__ float bfs(unsigned short u) {
  return __uint_as_float(((unsigned)u) << 16);
}
__device__ __forceinline__ float bflo(unsigned v) { return __uint_as_float(v << 16); }
__device__ __forceinline__ float bfhi(unsigned v) { return __uint_as_float(v & 0xFFFF0000u); }

// ---------------- edge counting ----------------
__global__ __launch_bounds__(256) void count_kernel(const int* __restrict__ dst,
                                                    int* __restrict__ cnt) {
  int e = blockIdx.x * 256 + threadIdx.x;
  if (e < NE) atomicAdd(&cnt[dst[e]], 1);
}

// ---------------- exclusive scan over cnt (3 kernels) ----------------
__global__ __launch_bounds__(256) void scan1(const int* __restrict__ cnt,
                                             int* __restrict__ partial) {
  int i = blockIdx.x * 256 + threadIdx.x;
  int v = (i < NN) ? cnt[i] : 0;
  __shared__ int sh[256];
  sh[threadIdx.x] = v;
  __syncthreads();
  for (int off = 128; off > 0; off >>= 1) {
    if (threadIdx.x < off) sh[threadIdx.x] += sh[threadIdx.x + off];
    __syncthreads();
  }
  if (threadIdx.x == 0) partial[blockIdx.x] = sh[0];
}

__global__ __launch_bounds__(256) void scan2(int* __restrict__ partial, int nb) {
  __shared__ int sh[256];
  int t = threadIdx.x;
  sh[t] = (t < nb) ? partial[t] : 0;
  __syncthreads();
  for (int off = 1; off < 256; off <<= 1) {
    int v = (t >= off) ? sh[t - off] : 0;
    __syncthreads();
    sh[t] += v;
    __syncthreads();
  }
  partial[t] = (t == 0) ? 0 : sh[t - 1];  // exclusive
}

__global__ __launch_bounds__(256) void scan3(const int* __restrict__ cnt,
                                             const int* __restrict__ partial,
                                             int* __restrict__ rowptr,
                                             float* __restrict__ dis) {
  int i = blockIdx.x * 256 + threadIdx.x;
  int t = threadIdx.x;
  int v = (i < NN) ? cnt[i] : 0;
  __shared__ int sh[256];
  sh[t] = v;
  __syncthreads();
  for (int off = 1; off < 256; off <<= 1) {
    int u = (t >= off) ? sh[t - off] : 0;
    __syncthreads();
    sh[t] += u;
    __syncthreads();
  }
  if (i < NN) {
    rowptr[i] = partial[blockIdx.x] + (sh[t] - v);
    dis[i] = rsqrtf((float)(v + 1));  // deg = indeg + 1 (self loop)
  }
}

// ---------------- CSR bucket fill ----------------
__global__ __launch_bounds__(256) void fill_kernel(const int* __restrict__ src,
                                                   const int* __restrict__ dst,
                                                   const int* __restrict__ rowptr,
                                                   int* __restrict__ fill,
                                                   int* __restrict__ csr_src) {
  int e = blockIdx.x * 256 + threadIdx.x;
  if (e < NE) {
    int d = dst[e];
    int p = atomicAdd(&fill[d], 1);
    csr_src[rowptr[d] + p] = src[e];
  }
}

// ---------------- xs = dis[node] * x  (fp32 -> bf16 prescale) ----------------
__global__ __launch_bounds__(256) void scale_x(const float* __restrict__ x,
                                               const float* __restrict__ dis,
                                               ushort4* __restrict__ xs) {
  int i = blockIdx.x * 256 + threadIdx.x;  // float4 index; grid exact (800000)
  float4 v = ((const float4*)x)[i];
  float d = dis[i >> 4];  // 16 float4 per 64-wide row
  xs[i] = make_ushort4(f2bf(v.x * d), f2bf(v.y * d), f2bf(v.z * d), f2bf(v.w * d));
}

// ---------------- weight prep: B^T in bf16, fragment row-major ---------------
// Bt1[128][64]  = W1^T ; Bt2[128][256] = [Wl;Wr]^T  (col-major over k)
__global__ __launch_bounds__(256) void prep_B(const float* __restrict__ W1,
                                              const float* __restrict__ Wl,
                                              const float* __restrict__ Wr,
                                              short* __restrict__ Bt1,
                                              short* __restrict__ Bt2) {
  int i = blockIdx.x * 256 + threadIdx.x;  // grid exact: 40960 threads
  if (i < 128 * 64) {
    int n = i >> 6, k = i & 63;
    Bt1[i] = (short)f2bf(W1[k * 128 + n]);
  } else {
    int j = i - 128 * 64;  // 128*256
    int n = j >> 8, k = j & 255;
    float wv = (k < 128) ? Wl[k * 128 + n] : Wr[(k - 128) * 128 + n];
    Bt2[j] = (short)f2bf(wv);
  }
}

// ---------------- GCN aggregation: xa = di*(xs[node] + sum_e xs[src]) -------
// 32 lanes x uint (2 feats) per node, 8 nodes/block; 8/4/1-unrolled gathers
__global__ __launch_bounds__(256) void gcn_agg(const unsigned* __restrict__ xs,
                                               const int* __restrict__ csr_src,
                                               const int* __restrict__ rowptr,
                                               const int* __restrict__ cnt,
                                               const float* __restrict__ dis,
                                               unsigned* __restrict__ xa) {
  int node = blockIdx.x * 8 + threadIdx.y;
  int lane = threadIdx.x;  // 0..31, 2 feats per lane
  float di = dis[node];
  unsigned sv = xs[node * 32 + lane];
  float ax = bflo(sv), ay = bfhi(sv);  // self loop: di * (di*x_node)
  int e = rowptr[node];
  int end = e + cnt[node];
  for (; e + 8 <= end; e += 8) {
    int s0 = csr_src[e + 0], s1 = csr_src[e + 1], s2 = csr_src[e + 2],
        s3 = csr_src[e + 3], s4 = csr_src[e + 4], s5 = csr_src[e + 5],
        s6 = csr_src[e + 6], s7 = csr_src[e + 7];
    unsigned v0 = xs[s0 * 32 + lane], v1 = xs[s1 * 32 + lane];
    unsigned v2 = xs[s2 * 32 + lane], v3 = xs[s3 * 32 + lane];
    unsigned v4 = xs[s4 * 32 + lane], v5 = xs[s5 * 32 + lane];
    unsigned v6 = xs[s6 * 32 + lane], v7 = xs[s7 * 32 + lane];
    ax += ((bflo(v0) + bflo(v1)) + (bflo(v2) + bflo(v3))) +
          ((bflo(v4) + bflo(v5)) + (bflo(v6) + bflo(v7)));
    ay += ((bfhi(v0) + bfhi(v1)) + (bfhi(v2) + bfhi(v3))) +
          ((bfhi(v4) + bfhi(v5)) + (bfhi(v6) + bfhi(v7)));
  }
  for (; e + 4 <= end; e += 4) {
    int s0 = csr_src[e + 0], s1 = csr_src[e + 1], s2 = csr_src[e + 2],
        s3 = csr_src[e + 3];
    unsigned v0 = xs[s0 * 32 + lane], v1 = xs[s1 * 32 + lane];
    unsigned v2 = xs[s2 * 32 + lane], v3 = xs[s3 * 32 + lane];
    ax += (bflo(v0) + bflo(v1)) + (bflo(v2) + bflo(v3));
    ay += (bfhi(v0) + bfhi(v1)) + (bfhi(v2) + bfhi(v3));
  }
  for (; e < end; ++e) {
    unsigned v = xs[csr_src[e] * 32 + lane];
    ax += bflo(v);
    ay += bfhi(v);
  }
  xa[node * 32 + lane] = (unsigned)f2bf(di * ax) | ((unsigned)f2bf(di * ay) << 16);
}

// ---------------- SAGE mean aggregation on bf16 h (128 feats) ---------------
// 32 lanes x uint2 (4 feats) per node, 8 nodes/block
__global__ __launch_bounds__(256) void sage_agg(const uint2* __restrict__ hb,
                                                const int* __restrict__ csr_src,
                                                const int* __restrict__ rowptr,
                                                const int* __restrict__ cnt,
                                                uint2* __restrict__ neighb) {
  int node = blockIdx.x * 8 + threadIdx.y;
  int lane = threadIdx.x;  // 0..31, 4 feats per lane
  float a0 = 0.f, a1 = 0.f, a2 = 0.f, a3 = 0.f;
  int num = cnt[node];
  int e = rowptr[node];
  int end = e + num;
  for (; e + 8 <= end; e += 8) {
    int s0 = csr_src[e + 0], s1 = csr_src[e + 1], s2 = csr_src[e + 2],
        s3 = csr_src[e + 3], s4 = csr_src[e + 4], s5 = csr_src[e + 5],
        s6 = csr_src[e + 6], s7 = csr_src[e + 7];
    uint2 v0 = hb[s0 * 32 + lane], v1 = hb[s1 * 32 + lane];
    uint2 v2 = hb[s2 * 32 + lane], v3 = hb[s3 * 32 + lane];
    uint2 v4 = hb[s4 * 32 + lane], v5 = hb[s5 * 32 + lane];
    uint2 v6 = hb[s6 * 32 + lane], v7 = hb[s7 * 32 + lane];
    a0 += ((bflo(v0.x) + bflo(v1.x)) + (bflo(v2.x) + bflo(v3.x))) +
          ((bflo(v4.x) + bflo(v5.x)) + (bflo(v6.x) + bflo(v7.x)));
    a1 += ((bfhi(v0.x) + bfhi(v1.x)) + (bfhi(v2.x) + bfhi(v3.x))) +
          ((bfhi(v4.x) + bfhi(v5.x)) + (bfhi(v6.x) + bfhi(v7.x)));
    a2 += ((bflo(v0.y) + bflo(v1.y)) + (bflo(v2.y) + bflo(v3.y))) +
          ((bflo(v4.y) + bflo(v5.y)) + (bflo(v6.y) + bflo(v7.y)));
    a3 += ((bfhi(v0.y) + bfhi(v1.y)) + (bfhi(v2.y) + bfhi(v3.y))) +
          ((bfhi(v4.y) + bfhi(v5.y)) + (bfhi(v6.y) + bfhi(v7.y)));
  }
  for (; e + 4 <= end; e += 4) {
    int s0 = csr_src[e + 0], s1 = csr_src[e + 1], s2 = csr_src[e + 2],
        s3 = csr_src[e + 3];
    uint2 v0 = hb[s0 * 32 + lane], v1 = hb[s1 * 32 + lane];
    uint2 v2 = hb[s2 * 32 + lane], v3 = hb[s3 * 32 + lane];
    a0 += (bflo(v0.x) + bflo(v1.x)) + (bflo(v2.x) + bflo(v3.x));
    a1 += (bfhi(v0.x) + bfhi(v1.x)) + (bfhi(v2.x) + bfhi(v3.x));
    a2 += (bflo(v0.y) + bflo(v1.y)) + (bflo(v2.y) + bflo(v3.y));
    a3 += (bfhi(v0.y) + bfhi(v1.y)) + (bfhi(v2.y) + bfhi(v3.y));
  }
  for (; e < end; ++e) {
    uint2 v = hb[csr_src[e] * 32 + lane];
    a0 += bflo(v.x);
    a1 += bfhi(v.x);
    a2 += bflo(v.y);
    a3 += bfhi(v.y);
  }
  float inv = 1.0f / fmaxf((float)num, 1.0f);
  uint2 o;
  o.x = (unsigned)f2bf(a0 * inv) | ((unsigned)f2bf(a1 * inv) << 16);
  o.y = (unsigned)f2bf(a2 * inv) | ((unsigned)f2bf(a3 * inv) << 16);
  neighb[node * 32 + lane] = o;
}

// ---------------- MFMA bf16 GEMM + LDS-transposed coalesced epilogue --------
// C[NN,128] = A1[NN,K1]@B1 (+ A2[NN,K2]@B2) + bias ; Bt = [128][K1+K2] bf16
// K-loop identical to R5 (barrier-free, B streamed from L2). Epilogue stages
// the 64x128 fp32 tile into LDS (stride 132: 2-way bank alias = free), then
// writes CONTIGUOUS float4 (fp32 out) / ushort4 (bf16 out) rows — 512B per
// 32 lanes per store instr, vs the previous 64B-granule dword scatter.
// BN column stats fused into the read phase (fixed 4-col group per thread).
template <int K1, int K2, bool OUTBF>
__global__ __launch_bounds__(256) void gemm_mfma(const short* __restrict__ A1,
                                                 const short* __restrict__ A2,
                                                 const short* __restrict__ Bt,
                                                 const float* __restrict__ bias,
                                                 float* __restrict__ Cf,
                                                 unsigned short* __restrict__ Cb,
                                                 float* __restrict__ sums,
                                                 float* __restrict__ sumsq) {
  constexpr int KT = K1 + K2;
  constexpr int NK = KT / 32;  // total k-steps
  __shared__ float Cs[64 * 132];
  __shared__ float lsum[128], lsq[128];
  int tid = threadIdx.x;
  int lane = tid & 63;
  int w = tid >> 6;   // wave id -> n-tile pair
  int r = lane & 15;  // A/B row-in-tile; C col
  int q = lane >> 4;  // k-quad; C row-quad
  int row_base = blockIdx.x * 64;
  if (tid < 128) { lsum[tid] = 0.f; lsq[tid] = 0.f; }

  // B-frags for this wave's 2 n-tiles (compiler may stream from L2 - fine)
  short8 bfr[2][NK];
#pragma unroll
  for (int nn = 0; nn < 2; ++nn) {
    const short* bp = Bt + (size_t)((w * 2 + nn) * 16 + r) * KT + q * 8;
#pragma unroll
    for (int kk = 0; kk < NK; ++kk) bfr[nn][kk] = *(const short8*)(bp + kk * 32);
  }

  int rows[4];
#pragma unroll
  for (int m = 0; m < 4; ++m) {
    int rr = row_base + m * 16 + r;
    rows[m] = rr < NN ? rr : NN - 1;  // clamp: garbage rows never stored
  }

  f32x4 acc[4][2];
#pragma unroll
  for (int m = 0; m < 4; ++m)
#pragma unroll
    for (int nn = 0; nn < 2; ++nn) acc[m][nn] = (f32x4){0.f, 0.f, 0.f, 0.f};

#pragma unroll
  for (int kk = 0; kk < K1 / 32; ++kk) {
    short8 af[4];
#pragma unroll
    for (int m = 0; m < 4; ++m)
      af[m] = *(const short8*)(A1 + (size_t)rows[m] * K1 + kk * 32 + q * 8);
#pragma unroll
    for (int m = 0; m < 4; ++m)
#pragma unroll
      for (int nn = 0; nn < 2; ++nn)
        acc[m][nn] =
            __builtin_amdgcn_mfma_f32_16x16x32_bf16(af[m], bfr[nn][kk], acc[m][nn], 0, 0, 0);
  }
  if constexpr (K2 > 0) {
#pragma unroll
    for (int kk = 0; kk < K2 / 32; ++kk) {
      short8 af[4];
#pragma unroll
      for (int m = 0; m < 4; ++m)
        af[m] = *(const short8*)(A2 + (size_t)rows[m] * K2 + kk * 32 + q * 8);
#pragma unroll
      for (int m = 0; m < 4; ++m)
#pragma unroll
        for (int nn = 0; nn < 2; ++nn)
          acc[m][nn] = __builtin_amdgcn_mfma_f32_16x16x32_bf16(
              af[m], bfr[nn][K1 / 32 + kk], acc[m][nn], 0, 0, 0);
    }
  }

  // stage tile (+bias) into LDS
  float bias_r[2];
#pragma unroll
  for (int nn = 0; nn < 2; ++nn) bias_r[nn] = bias[(w * 2 + nn) * 16 + r];
#pragma unroll
  for (int m = 0; m < 4; ++m)
#pragma unroll
    for (int i = 0; i < 4; ++i)
#pragma unroll
      for (int nn = 0; nn < 2; ++nn)
        Cs[(m * 16 + q * 4 + i) * 132 + (w * 2 + nn) * 16 + r] =
            acc[m][nn][i] + bias_r[nn];
  __syncthreads();

  // coalesced write phase + column stats (thread owns cols c4*4..c4*4+3)
  int c4 = tid & 31;
  float cs[4] = {0.f, 0.f, 0.f, 0.f}, cq[4] = {0.f, 0.f, 0.f, 0.f};
#pragma unroll
  for (int j = 0; j < 8; ++j) {
    int idx = tid + 256 * j;
    int rr = idx >> 5;
    int grow = row_base + rr;
    if (grow < NN) {
      float4 v = *(const float4*)&Cs[rr * 132 + c4 * 4];
      if constexpr (OUTBF) {
        *(ushort4*)&Cb[(size_t)grow * 128 + c4 * 4] =
            make_ushort4(f2bf(v.x), f2bf(v.y), f2bf(v.z), f2bf(v.w));
      } else {
        *(float4*)&Cf[(size_t)grow * 128 + c4 * 4] = v;
      }
      cs[0] += v.x; cq[0] += v.x * v.x;
      cs[1] += v.y; cq[1] += v.y * v.y;
      cs[2] += v.z; cq[2] += v.z * v.z;
      cs[3] += v.w; cq[3] += v.w * v.w;
    }
  }
  // lanes l and l^32 share the same col group
#pragma unroll
  for (int k = 0; k < 4; ++k) {
    cs[k] += __shfl_xor(cs[k], 32);
    cq[k] += __shfl_xor(cq[k], 32);
  }
  if (lane < 32) {
#pragma unroll
    for (int k = 0; k < 4; ++k) {
      atomicAdd(&lsum[c4 * 4 + k], cs[k]);  // 4 waves -> 4-way, trivial
      atomicAdd(&lsq[c4 * 4 + k], cq[k]);
    }
  }
  __syncthreads();
  if (tid < 128) {
    atomicAdd(&sums[tid], lsum[tid]);
    atomicAdd(&sumsq[tid], lsq[tid]);
  }
}

// ---------------- BN finalize (in-block) + apply + ReLU, bf16 in-place ------
__global__ __launch_bounds__(256) void bn_apply_bf(unsigned* __restrict__ hb,
                                                   const float* __restrict__ sums,
                                                   const float* __restrict__ sumsq,
                                                   const float* __restrict__ gamma,
                                                   const float* __restrict__ beta) {
  __shared__ float sc[128], sh[128];
  int t = threadIdx.x;
  if (t < 128) {
    float mean = sums[t] * (1.0f / NN);
    float var = fmaxf(sumsq[t] * (1.0f / NN) - mean * mean, 0.f);
    float inv = rsqrtf(var + BN_EPS);
    float s = gamma[t] * inv;
    sc[t] = s;
    sh[t] = beta[t] - mean * s;
  }
  __syncthreads();
  int i = blockIdx.x * 256 + t;  // uint2 index; grid exact
  uint2 v = ((uint2*)hb)[i];
  int c = (i & 31) * 4;
  float f0 = fmaxf(fmaf(bflo(v.x), sc[c + 0], sh[c + 0]), 0.f);
  float f1 = fmaxf(fmaf(bfhi(v.x), sc[c + 1], sh[c + 1]), 0.f);
  float f2 = fmaxf(fmaf(bflo(v.y), sc[c + 2], sh[c + 2]), 0.f);
  float f3 = fmaxf(fmaf(bfhi(v.y), sc[c + 3], sh[c + 3]), 0.f);
  v.x = (unsigned)f2bf(f0) | ((unsigned)f2bf(f1) << 16);
  v.y = (unsigned)f2bf(f2) | ((unsigned)f2bf(f3) << 16);
  ((uint2*)hb)[i] = v;
}

// ---------------- BN finalize (in-block) + apply + ReLU, fp32 in-place ------
__global__ __launch_bounds__(256) void bn_apply_f32(float* __restrict__ out,
                                                    const float* __restrict__ sums,
                                                    const float* __restrict__ sumsq,
                                                    const float* __restrict__ gamma,
                                                    const float* __restrict__ beta) {
  __shared__ float sc[128], sh[128];
  int t = threadIdx.x;
  if (t < 128) {
    float mean = sums[t] * (1.0f / NN);
    float var = fmaxf(sumsq[t] * (1.0f / NN) - mean * mean, 0.f);
    float inv = rsqrtf(var + BN_EPS);
    float s = gamma[t] * inv;
    sc[t] = s;
    sh[t] = beta[t] - mean * s;
  }
  __syncthreads();
  int i4 = blockIdx.x * 256 + t;  // float4 index; grid exact
  float4 v = ((const float4*)out)[i4];
  int f = (i4 & 31) * 4;
  v.x = fmaxf(fmaf(v.x, sc[f + 0], sh[f + 0]), 0.f);
  v.y = fmaxf(fmaf(v.y, sc[f + 1], sh[f + 1]), 0.f);
  v.z = fmaxf(fmaf(v.z, sc[f + 2], sh[f + 2]), 0.f);
  v.w = fmaxf(fmaf(v.w, sc[f + 3], sh[f + 3]), 0.f);
  ((float4*)out)[i4] = v;
}

extern "C" void kernel_launch(void* const* d_in, const int* in_sizes, int n_in,
                              void* d_out, int out_size, void* d_ws, size_t ws_size,
                              hipStream_t stream) {
  const float* x   = (const float*)d_in[0];
  const int*   ei  = (const int*)d_in[1];
  const float* W1  = (const float*)d_in[2];
  const float* b1  = (const float*)d_in[3];
  const float* g1  = (const float*)d_in[4];
  const float* be1 = (const float*)d_in[5];
  const float* Wl  = (const float*)d_in[6];
  const float* bl  = (const float*)d_in[7];
  const float* Wr  = (const float*)d_in[8];
  const float* g2  = (const float*)d_in[9];
  const float* be2 = (const float*)d_in[10];
  const int* srcp = ei;
  const int* dstp = ei + NE;

  char* w = (char*)d_ws;
  auto alloc = [&](size_t bytes) {
    char* p = w;
    w += (bytes + 255) & ~(size_t)255;
    return p;
  };
  int*   cnt     = (int*)alloc((size_t)NN * 4);
  int*   fill    = (int*)alloc((size_t)NN * 4);
  int*   rowptr  = (int*)alloc((size_t)NN * 4);
  int*   partial = (int*)alloc(256 * 4);
  float* dis     = (float*)alloc((size_t)NN * 4);
  int*   csr     = (int*)alloc((size_t)NE * 4);
  unsigned short* xs     = (unsigned short*)alloc((size_t)NN * FIN * 2);
  unsigned short* xa     = (unsigned short*)alloc((size_t)NN * FIN * 2);
  unsigned short* hb     = (unsigned short*)alloc((size_t)NN * FHID * 2);
  unsigned*       neighb = (unsigned*)alloc((size_t)NN * FHID * 2);
  short* Bt1     = (short*)alloc(128 * 64 * 2);
  short* Bt2     = (short*)alloc(128 * 256 * 2);
  float* stats   = (float*)alloc(8 * 128 * 4);
  float* sums1 = stats,       *sumsq1 = stats + 128;
  float* sums2 = stats + 512, *sumsq2 = stats + 640;

  hipMemsetAsync(cnt, 0, (size_t)NN * 4, stream);
  hipMemsetAsync(fill, 0, (size_t)NN * 4, stream);
  hipMemsetAsync(stats, 0, 8 * 128 * 4, stream);

  int nbE = (NE + 255) / 256;
  int nbN = (NN + 255) / 256;  // 196 <= 256 (scan2 single-block limit)
  int nbG = (NN + 63) / 64;    // 782 MFMA blocks

  prep_B<<<160, 256, 0, stream>>>(W1, Wl, Wr, Bt1, Bt2);
  count_kernel<<<nbE, 256, 0, stream>>>(dstp, cnt);
  scan1<<<nbN, 256, 0, stream>>>(cnt, partial);
  scan2<<<1, 256, 0, stream>>>(partial, nbN);
  scan3<<<nbN, 256, 0, stream>>>(cnt, partial, rowptr, dis);
  fill_kernel<<<nbE, 256, 0, stream>>>(srcp, dstp, rowptr, fill, csr);
  scale_x<<<NN * FIN / 4 / 256, 256, 0, stream>>>(x, dis, (ushort4*)xs);

  // GCN: aggregate prescaled bf16 X, MFMA GEMM K=64 -> bf16 h
  gcn_agg<<<NN / 8, dim3(32, 8), 0, stream>>>((const unsigned*)xs, csr, rowptr, cnt,
                                              dis, (unsigned*)xa);
  gemm_mfma<64, 0, true><<<nbG, 256, 0, stream>>>(
      (const short*)xa, nullptr, Bt1, b1, nullptr, hb, sums1, sumsq1);
  bn_apply_bf<<<NN * FHID / 4 / 256, 256, 0, stream>>>((unsigned*)hb, sums1, sumsq1,
                                                       g1, be1);

  // SAGE: mean-agg bf16 h, fused K=256 MFMA GEMM -> fp32 d_out
  sage_agg<<<NN / 8, dim3(32, 8), 0, stream>>>((const uint2*)hb, csr, rowptr, cnt,
                                               (uint2*)neighb);
  gemm_mfma<128, 128, false><<<nbG, 256, 0, stream>>>(
      (const short*)neighb, (const short*)hb, Bt2, bl, (float*)d_out, nullptr,
      sums2, sumsq2);
  bn_apply_f32<<<NN * FHID / 4 / 256, 256, 0, stream>>>((float*)d_out, sums2, sumsq2,
                                                        g2, be2);
}